// Round 1
// baseline (1460.130 us; speedup 1.0000x reference)
//
#include <hip/hip_runtime.h>

#define NPTS 250000

typedef float4 f4;

// ---------------------------------------------------------------------------
// K1: h0 = relu(conv3(feats, w00));  t = relu(feats @ w10)
// block = 256 threads = 4 waves; each wave owns 8 points; block owns 32 points.
// lane -> (c = lane&31 output channel, kh = lane>>5 k-half). Center weights in
// VGPRs, feats rows staged in LDS (broadcast reads), k-half reduced via shfl.
// ---------------------------------------------------------------------------
__global__ __launch_bounds__(256) void k1_fused(
    const float* __restrict__ feats, const float* __restrict__ w00,
    const float* __restrict__ w10, const int* __restrict__ nbr,
    float* __restrict__ h0, float* __restrict__ t_out)
{
    __shared__ float xs[32][64];
    const int tid  = threadIdx.x;
    const int lane = tid & 63;
    const int wv   = tid >> 6;          // 0..3
    const int c    = lane & 31;
    const int kh   = lane >> 5;         // 0/1 -> k range [kh*32, kh*32+32)
    const int blockBase = blockIdx.x * 32;

    // stage feats rows for this block's 32 points (coalesced, float4)
    {
        const int n4 = min(32, NPTS - blockBase) * 16;   // float4 per valid rows
        const f4* __restrict__ src =
            reinterpret_cast<const f4*>(feats + (size_t)blockBase * 64);
        f4* dst = reinterpret_cast<f4*>(&xs[0][0]);
        #pragma unroll
        for (int v = 0; v < 2; ++v) {
            const int idx = tid + v * 256;
            if (idx < n4) dst[idx] = src[idx];
        }
    }

    // center weights (offset 13) + 1x1 weights into registers
    float wA[32], wB[32];
    #pragma unroll
    for (int kk = 0; kk < 32; ++kk) {
        const int k = kh * 32 + kk;
        wA[kk] = w00[(size_t)(13 * 64 + k) * 32 + c];
        wB[kk] = w10[(size_t)k * 32 + c];
    }
    __syncthreads();

    float acc0[8], acc1[8];
    const int pbase = wv * 8;
    const int gbase = blockBase + pbase;

    // center GEMM + 1x1 from LDS
    #pragma unroll
    for (int p = 0; p < 8; ++p) {
        const f4* xr = reinterpret_cast<const f4*>(&xs[pbase + p][kh * 32]);
        float a0 = 0.f, a1 = 0.f;
        #pragma unroll
        for (int q = 0; q < 8; ++q) {
            const f4 x = xr[q];
            a0 = fmaf(x.x, wA[4*q+0], a0); a1 = fmaf(x.x, wB[4*q+0], a1);
            a0 = fmaf(x.y, wA[4*q+1], a0); a1 = fmaf(x.y, wB[4*q+1], a1);
            a0 = fmaf(x.z, wA[4*q+2], a0); a1 = fmaf(x.z, wB[4*q+2], a1);
            a0 = fmaf(x.w, wA[4*q+3], a0); a1 = fmaf(x.w, wB[4*q+3], a1);
        }
        acc0[p] = a0; acc1[p] = a1;
    }

    // sparse neighbor contributions (o != 13), ballot-scan over 27 offsets
    #pragma unroll
    for (int p = 0; p < 8; ++p) {
        const int i = gbase + p;
        if (i >= NPTS) break;                 // wave-uniform
        int v = -1;
        if (lane < 27) v = nbr[(size_t)i * 27 + lane];
        const bool valid = (lane < 27) && (v >= 0) && (lane != 13);
        unsigned long long m = __ballot(valid);
        float a0 = acc0[p];
        while (m) {
            const int o = __builtin_ctzll(m);
            m &= m - 1;
            const int j = __shfl(v, o);
            const f4* xr = reinterpret_cast<const f4*>(feats + (size_t)j * 64 + kh * 32);
            const float* w = w00 + (size_t)(o * 64 + kh * 32) * 32 + c;
            #pragma unroll
            for (int q = 0; q < 8; ++q) {
                const f4 x = xr[q];
                a0 = fmaf(x.x, w[(4*q+0)*32], a0);
                a0 = fmaf(x.y, w[(4*q+1)*32], a0);
                a0 = fmaf(x.z, w[(4*q+2)*32], a0);
                a0 = fmaf(x.w, w[(4*q+3)*32], a0);
            }
        }
        acc0[p] = a0;
    }

    // k-half reduce + relu + store (kh0 lanes -> h0, kh1 lanes -> t)
    #pragma unroll
    for (int p = 0; p < 8; ++p) {
        const int i = gbase + p;
        if (i >= NPTS) break;                 // wave-uniform
        const float a0 = acc0[p] + __shfl_xor(acc0[p], 32);
        const float a1 = acc1[p] + __shfl_xor(acc1[p], 32);
        if (kh == 0) h0[(size_t)i * 32 + c]    = fmaxf(a0, 0.f);
        else         t_out[(size_t)i * 32 + c] = fmaxf(a1, 0.f);
    }
}

// ---------------------------------------------------------------------------
// K2: out[:, 0:32] = conv3(h0, w01) + feats[:, 0:32]
//     t2 = relu(conv3(t, w11)); out[:, 32:64] = t2 @ w12 + feats[:, 32:64]
// Same mapping; k-half is 16 wide (Cin = 32 here).
// ---------------------------------------------------------------------------
__global__ __launch_bounds__(256) void k2_fused(
    const float* __restrict__ h0, const float* __restrict__ t_in,
    const float* __restrict__ w01, const float* __restrict__ w11,
    const float* __restrict__ w12, const float* __restrict__ feats,
    const int* __restrict__ nbr, float* __restrict__ out)
{
    __shared__ float hs[32][32];
    __shared__ float ts[32][32];
    __shared__ float t2s[32][32];
    const int tid  = threadIdx.x;
    const int lane = tid & 63;
    const int wv   = tid >> 6;
    const int c    = lane & 31;
    const int kh   = lane >> 5;         // k range [kh*16, kh*16+16)
    const int blockBase = blockIdx.x * 32;

    // stage h0/t rows for this block's points
    {
        const int n4 = min(32, NPTS - blockBase) * 8;
        const f4* __restrict__ srcH =
            reinterpret_cast<const f4*>(h0 + (size_t)blockBase * 32);
        const f4* __restrict__ srcT =
            reinterpret_cast<const f4*>(t_in + (size_t)blockBase * 32);
        if (tid < n4) {
            reinterpret_cast<f4*>(&hs[0][0])[tid] = srcH[tid];
            reinterpret_cast<f4*>(&ts[0][0])[tid] = srcT[tid];
        }
    }

    float wA[16], wB[16], wC[16];
    #pragma unroll
    for (int kk = 0; kk < 16; ++kk) {
        const int k = kh * 16 + kk;
        wA[kk] = w01[(size_t)(13 * 32 + k) * 32 + c];
        wB[kk] = w11[(size_t)(13 * 32 + k) * 32 + c];
        wC[kk] = w12[(size_t)k * 32 + c];
    }
    __syncthreads();

    float acc0[8], acc1[8];
    const int pbase = wv * 8;
    const int gbase = blockBase + pbase;

    // center
    #pragma unroll
    for (int p = 0; p < 8; ++p) {
        const f4* hr = reinterpret_cast<const f4*>(&hs[pbase + p][kh * 16]);
        const f4* tr = reinterpret_cast<const f4*>(&ts[pbase + p][kh * 16]);
        float a0 = 0.f, a1 = 0.f;
        #pragma unroll
        for (int q = 0; q < 4; ++q) {
            const f4 h = hr[q];
            a0 = fmaf(h.x, wA[4*q+0], a0);
            a0 = fmaf(h.y, wA[4*q+1], a0);
            a0 = fmaf(h.z, wA[4*q+2], a0);
            a0 = fmaf(h.w, wA[4*q+3], a0);
            const f4 u = tr[q];
            a1 = fmaf(u.x, wB[4*q+0], a1);
            a1 = fmaf(u.y, wB[4*q+1], a1);
            a1 = fmaf(u.z, wB[4*q+2], a1);
            a1 = fmaf(u.w, wB[4*q+3], a1);
        }
        acc0[p] = a0; acc1[p] = a1;
    }

    // sparse neighbors
    #pragma unroll
    for (int p = 0; p < 8; ++p) {
        const int i = gbase + p;
        if (i >= NPTS) break;
        int v = -1;
        if (lane < 27) v = nbr[(size_t)i * 27 + lane];
        const bool valid = (lane < 27) && (v >= 0) && (lane != 13);
        unsigned long long m = __ballot(valid);
        float a0 = acc0[p], a1 = acc1[p];
        while (m) {
            const int o = __builtin_ctzll(m);
            m &= m - 1;
            const int j = __shfl(v, o);
            const f4* hr = reinterpret_cast<const f4*>(h0  + (size_t)j * 32 + kh * 16);
            const f4* tr = reinterpret_cast<const f4*>(t_in + (size_t)j * 32 + kh * 16);
            const float* wa = w01 + (size_t)(o * 32 + kh * 16) * 32 + c;
            const float* wb = w11 + (size_t)(o * 32 + kh * 16) * 32 + c;
            #pragma unroll
            for (int q = 0; q < 4; ++q) {
                const f4 h = hr[q];
                a0 = fmaf(h.x, wa[(4*q+0)*32], a0);
                a0 = fmaf(h.y, wa[(4*q+1)*32], a0);
                a0 = fmaf(h.z, wa[(4*q+2)*32], a0);
                a0 = fmaf(h.w, wa[(4*q+3)*32], a0);
                const f4 u = tr[q];
                a1 = fmaf(u.x, wb[(4*q+0)*32], a1);
                a1 = fmaf(u.y, wb[(4*q+1)*32], a1);
                a1 = fmaf(u.z, wb[(4*q+2)*32], a1);
                a1 = fmaf(u.w, wb[(4*q+3)*32], a1);
            }
        }
        acc0[p] = a0; acc1[p] = a1;
    }

    // reduce k-halves; t2 -> LDS (need full 32-vector per point for @w12)
    float a0f[8];
    #pragma unroll
    for (int p = 0; p < 8; ++p) {
        const int i = gbase + p;
        if (i < NPTS) {
            a0f[p] = acc0[p] + __shfl_xor(acc0[p], 32);
            const float a1 = acc1[p] + __shfl_xor(acc1[p], 32);
            if (kh == 0) t2s[pbase + p][c] = fmaxf(a1, 0.f);
        }
    }
    __syncthreads();

    // out1 = t2 @ w12 ; residual add; store
    #pragma unroll
    for (int p = 0; p < 8; ++p) {
        const int i = gbase + p;
        if (i >= NPTS) break;
        const f4* t2r = reinterpret_cast<const f4*>(&t2s[pbase + p][kh * 16]);
        float o1 = 0.f;
        #pragma unroll
        for (int q = 0; q < 4; ++q) {
            const f4 x = t2r[q];
            o1 = fmaf(x.x, wC[4*q+0], o1);
            o1 = fmaf(x.y, wC[4*q+1], o1);
            o1 = fmaf(x.z, wC[4*q+2], o1);
            o1 = fmaf(x.w, wC[4*q+3], o1);
        }
        o1 += __shfl_xor(o1, 32);
        const float res = feats[(size_t)i * 64 + kh * 32 + c];
        const float val = (kh == 0 ? a0f[p] : o1) + res;
        out[(size_t)i * 64 + kh * 32 + c] = val;
    }
}

extern "C" void kernel_launch(void* const* d_in, const int* in_sizes, int n_in,
                              void* d_out, int out_size, void* d_ws, size_t ws_size,
                              hipStream_t stream)
{
    const float* feats = (const float*)d_in[0];
    const float* w00   = (const float*)d_in[1];
    const float* w01   = (const float*)d_in[2];
    const float* w10   = (const float*)d_in[3];
    const float* w11   = (const float*)d_in[4];
    const float* w12   = (const float*)d_in[5];
    const int*   nbr   = (const int*)d_in[6];
    float* out = (float*)d_out;

    float* h0 = (float*)d_ws;                  // [N,32] f32
    float* t  = h0 + (size_t)NPTS * 32;        // [N,32] f32

    const int blocks = (NPTS + 31) / 32;       // 32 points per block
    k1_fused<<<blocks, 256, 0, stream>>>(feats, w00, w10, nbr, h0, t);
    k2_fused<<<blocks, 256, 0, stream>>>(h0, t, w01, w11, w12, feats, nbr, out);
}

// Round 5
// 997.107 us; speedup vs baseline: 1.4644x; 1.4644x over previous
//
#include <hip/hip_runtime.h>

#define NPTS 250000

typedef float4 f4;

// ---------------------------------------------------------------------------
// block = 256 thr = 4 waves; each wave owns 4 points. Lane -> (c = lane&31
// output channel, kh = lane>>5 k-half). Per wave: 1 float4 load stages all 4
// feats rows into LDS (one __syncthreads after staging), 1 int2 load grabs
// all 108 nbr entries; sparse events iterated from two ballot masks.
// t2 -> out1 GEMM in k2 is done via __shfl broadcasts (no LDS, no hazard).
// 250000 = 15625 blocks * 16 points exactly.
// ---------------------------------------------------------------------------

__device__ __forceinline__ void k1_event(int f, int j, int kh, int c,
    const float* __restrict__ feats, const float* __restrict__ w00,
    float& a00, float& a01, float& a02, float& a03)
{
    const int p = f / 27, o = f % 27;
    const f4* __restrict__ xr = reinterpret_cast<const f4*>(feats + (size_t)j * 64 + kh * 32);
    const float* __restrict__ w = w00 + (size_t)(o * 64 + kh * 32) * 32 + c;
    float a = 0.f;
    #pragma unroll
    for (int q = 0; q < 8; ++q) {
        const f4 x = xr[q];
        a = fmaf(x.x, w[(4*q+0)*32], a);
        a = fmaf(x.y, w[(4*q+1)*32], a);
        a = fmaf(x.z, w[(4*q+2)*32], a);
        a = fmaf(x.w, w[(4*q+3)*32], a);
    }
    if      (p == 0) a00 += a;
    else if (p == 1) a01 += a;
    else if (p == 2) a02 += a;
    else             a03 += a;
}

__global__ __launch_bounds__(256, 4) void k1(
    const float* __restrict__ feats, const float* __restrict__ w00,
    const float* __restrict__ w10, const int* __restrict__ nbr,
    float* __restrict__ h0, float* __restrict__ t_out)
{
    __shared__ f4 xs[4][64];
    const int tid  = threadIdx.x;
    const int lane = tid & 63;
    const int wv   = tid >> 6;
    const int c    = lane & 31;
    const int kh   = lane >> 5;
    const int i0   = blockIdx.x * 16 + wv * 4;   // wave's first point

    // front-load: 1 f4 (4 rows of feats), 1 int2 (108 nbr entries)
    const f4 xv = reinterpret_cast<const f4*>(feats + (size_t)i0 * 64)[lane];
    int2 nv = make_int2(-1, -1);
    if (lane < 54) nv = reinterpret_cast<const int2*>(nbr + (size_t)i0 * 27)[lane];

    // center + 1x1 weights -> VGPRs (coalesced per-lane c; L1/L2-warm)
    float wA[32], wB[32];
    #pragma unroll
    for (int kk = 0; kk < 32; ++kk) {
        const int k = kh * 32 + kk;
        wA[kk] = w00[(size_t)(13 * 64 + k) * 32 + c];
        wB[kk] = w10[(size_t)k * 32 + c];
    }

    xs[wv][lane] = xv;
    __syncthreads();      // harden LDS write->read ordering

    float a00 = 0, a01 = 0, a02 = 0, a03 = 0;   // conv path
    float a10 = 0, a11 = 0, a12 = 0, a13 = 0;   // 1x1 path
    #pragma unroll
    for (int p = 0; p < 4; ++p) {
        const f4* xr = &xs[wv][p * 16 + kh * 8];
        float a0 = 0.f, a1 = 0.f;
        #pragma unroll
        for (int q = 0; q < 8; ++q) {
            const f4 x = xr[q];
            a0 = fmaf(x.x, wA[4*q+0], a0); a1 = fmaf(x.x, wB[4*q+0], a1);
            a0 = fmaf(x.y, wA[4*q+1], a0); a1 = fmaf(x.y, wB[4*q+1], a1);
            a0 = fmaf(x.z, wA[4*q+2], a0); a1 = fmaf(x.z, wB[4*q+2], a1);
            a0 = fmaf(x.w, wA[4*q+3], a0); a1 = fmaf(x.w, wB[4*q+3], a1);
        }
        if      (p == 0) { a00 = a0; a10 = a1; }
        else if (p == 1) { a01 = a0; a11 = a1; }
        else if (p == 2) { a02 = a0; a12 = a1; }
        else             { a03 = a0; a13 = a1; }
    }

    // sparse events: flat f = 2*lane+e in [0,108) -> point f/27, offset f%27
    unsigned long long b0 = __ballot(lane < 54 && nv.x >= 0 && ((2 * lane    ) % 27) != 13);
    unsigned long long b1 = __ballot(lane < 54 && nv.y >= 0 && ((2 * lane + 1) % 27) != 13);
    while (b0) {
        const int L = __builtin_ctzll(b0); b0 &= b0 - 1;
        const int j = __shfl(nv.x, L);
        k1_event(2 * L, j, kh, c, feats, w00, a00, a01, a02, a03);
    }
    while (b1) {
        const int L = __builtin_ctzll(b1); b1 &= b1 - 1;
        const int j = __shfl(nv.y, L);
        k1_event(2 * L + 1, j, kh, c, feats, w00, a00, a01, a02, a03);
    }

    #pragma unroll
    for (int p = 0; p < 4; ++p) {
        float a0 = (p == 0) ? a00 : (p == 1) ? a01 : (p == 2) ? a02 : a03;
        float a1 = (p == 0) ? a10 : (p == 1) ? a11 : (p == 2) ? a12 : a13;
        a0 += __shfl_xor(a0, 32);
        a1 += __shfl_xor(a1, 32);
        const int i = i0 + p;
        if (kh == 0) h0[(size_t)i * 32 + c]    = fmaxf(a0, 0.f);
        else         t_out[(size_t)i * 32 + c] = fmaxf(a1, 0.f);
    }
}

__device__ __forceinline__ void k2_event(int f, int j, int kh, int c,
    const float* __restrict__ h0, const float* __restrict__ t_in,
    const float* __restrict__ w01, const float* __restrict__ w11,
    float& a00, float& a01, float& a02, float& a03,
    float& a10, float& a11, float& a12, float& a13)
{
    const int p = f / 27, o = f % 27;
    const f4* __restrict__ hr = reinterpret_cast<const f4*>(h0   + (size_t)j * 32 + kh * 16);
    const f4* __restrict__ tr = reinterpret_cast<const f4*>(t_in + (size_t)j * 32 + kh * 16);
    const float* __restrict__ wa = w01 + (size_t)(o * 32 + kh * 16) * 32 + c;
    const float* __restrict__ wb = w11 + (size_t)(o * 32 + kh * 16) * 32 + c;
    float a = 0.f, b = 0.f;
    #pragma unroll
    for (int q = 0; q < 4; ++q) {
        const f4 h = hr[q];
        a = fmaf(h.x, wa[(4*q+0)*32], a);
        a = fmaf(h.y, wa[(4*q+1)*32], a);
        a = fmaf(h.z, wa[(4*q+2)*32], a);
        a = fmaf(h.w, wa[(4*q+3)*32], a);
        const f4 u = tr[q];
        b = fmaf(u.x, wb[(4*q+0)*32], b);
        b = fmaf(u.y, wb[(4*q+1)*32], b);
        b = fmaf(u.z, wb[(4*q+2)*32], b);
        b = fmaf(u.w, wb[(4*q+3)*32], b);
    }
    if      (p == 0) { a00 += a; a10 += b; }
    else if (p == 1) { a01 += a; a11 += b; }
    else if (p == 2) { a02 += a; a12 += b; }
    else             { a03 += a; a13 += b; }
}

__global__ __launch_bounds__(256, 4) void k2(
    const float* __restrict__ h0, const float* __restrict__ t_in,
    const float* __restrict__ w01, const float* __restrict__ w11,
    const float* __restrict__ w12, const float* __restrict__ feats,
    const int* __restrict__ nbr, float* __restrict__ out)
{
    __shared__ float2 hs[4][64];
    __shared__ float2 ts[4][64];
    const int tid  = threadIdx.x;
    const int lane = tid & 63;
    const int wv   = tid >> 6;
    const int c    = lane & 31;
    const int kh   = lane >> 5;
    const int i0   = blockIdx.x * 16 + wv * 4;

    const float2 hv = reinterpret_cast<const float2*>(h0   + (size_t)i0 * 32)[lane];
    const float2 tv = reinterpret_cast<const float2*>(t_in + (size_t)i0 * 32)[lane];
    int2 nv = make_int2(-1, -1);
    if (lane < 54) nv = reinterpret_cast<const int2*>(nbr + (size_t)i0 * 27)[lane];

    float wA[16], wB[16], wC[16];
    #pragma unroll
    for (int kk = 0; kk < 16; ++kk) {
        const int k = kh * 16 + kk;
        wA[kk] = w01[(size_t)(13 * 32 + k) * 32 + c];
        wB[kk] = w11[(size_t)(13 * 32 + k) * 32 + c];
        wC[kk] = w12[(size_t)k * 32 + c];
    }

    hs[wv][lane] = hv;
    ts[wv][lane] = tv;
    __syncthreads();      // harden LDS write->read ordering

    float a00 = 0, a01 = 0, a02 = 0, a03 = 0;   // conv0_1 path
    float a10 = 0, a11 = 0, a12 = 0, a13 = 0;   // conv1_1 path
    #pragma unroll
    for (int p = 0; p < 4; ++p) {
        const f4* hr = reinterpret_cast<const f4*>(&hs[wv][p * 16]) + kh * 4;
        const f4* tr = reinterpret_cast<const f4*>(&ts[wv][p * 16]) + kh * 4;
        float a0 = 0.f, a1 = 0.f;
        #pragma unroll
        for (int q = 0; q < 4; ++q) {
            const f4 h = hr[q];
            a0 = fmaf(h.x, wA[4*q+0], a0);
            a0 = fmaf(h.y, wA[4*q+1], a0);
            a0 = fmaf(h.z, wA[4*q+2], a0);
            a0 = fmaf(h.w, wA[4*q+3], a0);
            const f4 u = tr[q];
            a1 = fmaf(u.x, wB[4*q+0], a1);
            a1 = fmaf(u.y, wB[4*q+1], a1);
            a1 = fmaf(u.z, wB[4*q+2], a1);
            a1 = fmaf(u.w, wB[4*q+3], a1);
        }
        if      (p == 0) { a00 = a0; a10 = a1; }
        else if (p == 1) { a01 = a0; a11 = a1; }
        else if (p == 2) { a02 = a0; a12 = a1; }
        else             { a03 = a0; a13 = a1; }
    }

    unsigned long long b0 = __ballot(lane < 54 && nv.x >= 0 && ((2 * lane    ) % 27) != 13);
    unsigned long long b1 = __ballot(lane < 54 && nv.y >= 0 && ((2 * lane + 1) % 27) != 13);
    while (b0) {
        const int L = __builtin_ctzll(b0); b0 &= b0 - 1;
        const int j = __shfl(nv.x, L);
        k2_event(2 * L, j, kh, c, h0, t_in, w01, w11, a00, a01, a02, a03, a10, a11, a12, a13);
    }
    while (b1) {
        const int L = __builtin_ctzll(b1); b1 &= b1 - 1;
        const int j = __shfl(nv.y, L);
        k2_event(2 * L + 1, j, kh, c, h0, t_in, w01, w11, a00, a01, a02, a03, a10, a11, a12, a13);
    }

    // finalize: t2 = relu(conv1_1 full); out1 = t2 @ w12 via shfl broadcasts
    #pragma unroll
    for (int p = 0; p < 4; ++p) {
        float a0 = (p == 0) ? a00 : (p == 1) ? a01 : (p == 2) ? a02 : a03;
        float a1 = (p == 0) ? a10 : (p == 1) ? a11 : (p == 2) ? a12 : a13;
        a0 += __shfl_xor(a0, 32);
        a1 += __shfl_xor(a1, 32);
        const float t2 = fmaxf(a1, 0.f);   // full value for channel c, both halves
        float o1 = 0.f;
        #pragma unroll
        for (int kk = 0; kk < 16; ++kk) {
            const float tk = __shfl(t2, kh * 16 + kk);   // channel kh*16+kk
            o1 = fmaf(tk, wC[kk], o1);
        }
        o1 += __shfl_xor(o1, 32);
        const int i = i0 + p;
        const float res = feats[(size_t)i * 64 + kh * 32 + c];
        out[(size_t)i * 64 + kh * 32 + c] = (kh == 0 ? a0 : o1) + res;
    }
}

extern "C" void kernel_launch(void* const* d_in, const int* in_sizes, int n_in,
                              void* d_out, int out_size, void* d_ws, size_t ws_size,
                              hipStream_t stream)
{
    const float* feats = (const float*)d_in[0];
    const float* w00   = (const float*)d_in[1];
    const float* w01   = (const float*)d_in[2];
    const float* w10   = (const float*)d_in[3];
    const float* w11   = (const float*)d_in[4];
    const float* w12   = (const float*)d_in[5];
    const int*   nbr   = (const int*)d_in[6];
    float* out = (float*)d_out;

    float* h0 = (float*)d_ws;                  // [N,32] f32
    float* t  = h0 + (size_t)NPTS * 32;        // [N,32] f32

    const int blocks = NPTS / 16;              // 15625, exact
    k1<<<blocks, 256, 0, stream>>>(feats, w00, w10, nbr, h0, t);
    k2<<<blocks, 256, 0, stream>>>(h0, t, w01, w11, w12, feats, nbr, out);
}

// Round 6
// 454.340 us; speedup vs baseline: 3.2137x; 2.1946x over previous
//
#include <hip/hip_runtime.h>

#define NPTS 250000

typedef float4 f4;

// ---------------------------------------------------------------------------
// block = 256 thr = 4 waves; each wave owns 4 points. Lane -> (c = lane&31
// output channel, kh = lane>>5 k-half). Per wave: 1 float4 load stages all 4
// feats rows into LDS (one __syncthreads after staging), 1 int2 load grabs
// all 108 nbr entries; sparse events iterated from two ballot masks.
// t2 -> out1 GEMM in k2 via __shfl broadcasts (no LDS hazard).
// NOTE: __launch_bounds__(256) ONLY — the (256,4) variant forced a 64-VGPR
// allocation and spilled wA/wB to scratch (1.9 GB HBM writes, R5 counters).
// ---------------------------------------------------------------------------

__device__ __forceinline__ void k1_event(int f, int j, int kh, int c,
    const float* __restrict__ feats, const float* __restrict__ w00,
    float& a00, float& a01, float& a02, float& a03)
{
    const int p = f / 27, o = f % 27;
    const f4* __restrict__ xr = reinterpret_cast<const f4*>(feats + (size_t)j * 64 + kh * 32);
    const float* __restrict__ w = w00 + (size_t)(o * 64 + kh * 32) * 32 + c;
    float a = 0.f;
    #pragma unroll
    for (int q = 0; q < 8; ++q) {
        const f4 x = xr[q];
        a = fmaf(x.x, w[(4*q+0)*32], a);
        a = fmaf(x.y, w[(4*q+1)*32], a);
        a = fmaf(x.z, w[(4*q+2)*32], a);
        a = fmaf(x.w, w[(4*q+3)*32], a);
    }
    if      (p == 0) a00 += a;
    else if (p == 1) a01 += a;
    else if (p == 2) a02 += a;
    else             a03 += a;
}

__global__ __launch_bounds__(256) void k1(
    const float* __restrict__ feats, const float* __restrict__ w00,
    const float* __restrict__ w10, const int* __restrict__ nbr,
    float* __restrict__ h0, float* __restrict__ t_out)
{
    __shared__ f4 xs[4][64];
    const int tid  = threadIdx.x;
    const int lane = tid & 63;
    const int wv   = tid >> 6;
    const int c    = lane & 31;
    const int kh   = lane >> 5;
    const int i0   = blockIdx.x * 16 + wv * 4;   // wave's first point

    // front-load: 1 f4 (4 rows of feats), 1 int2 (108 nbr entries)
    const f4 xv = reinterpret_cast<const f4*>(feats + (size_t)i0 * 64)[lane];
    int2 nv = make_int2(-1, -1);
    if (lane < 54) nv = reinterpret_cast<const int2*>(nbr + (size_t)i0 * 27)[lane];

    // center + 1x1 weights -> VGPRs (coalesced per-lane c; L1/L2-warm)
    float wA[32], wB[32];
    #pragma unroll
    for (int kk = 0; kk < 32; ++kk) {
        const int k = kh * 32 + kk;
        wA[kk] = w00[(size_t)(13 * 64 + k) * 32 + c];
        wB[kk] = w10[(size_t)k * 32 + c];
    }

    xs[wv][lane] = xv;
    __syncthreads();      // harden LDS write->read ordering

    float a00 = 0, a01 = 0, a02 = 0, a03 = 0;   // conv path
    float a10 = 0, a11 = 0, a12 = 0, a13 = 0;   // 1x1 path
    #pragma unroll
    for (int p = 0; p < 4; ++p) {
        const f4* xr = &xs[wv][p * 16 + kh * 8];
        float a0 = 0.f, a1 = 0.f;
        #pragma unroll
        for (int q = 0; q < 8; ++q) {
            const f4 x = xr[q];
            a0 = fmaf(x.x, wA[4*q+0], a0); a1 = fmaf(x.x, wB[4*q+0], a1);
            a0 = fmaf(x.y, wA[4*q+1], a0); a1 = fmaf(x.y, wB[4*q+1], a1);
            a0 = fmaf(x.z, wA[4*q+2], a0); a1 = fmaf(x.z, wB[4*q+2], a1);
            a0 = fmaf(x.w, wA[4*q+3], a0); a1 = fmaf(x.w, wB[4*q+3], a1);
        }
        if      (p == 0) { a00 = a0; a10 = a1; }
        else if (p == 1) { a01 = a0; a11 = a1; }
        else if (p == 2) { a02 = a0; a12 = a1; }
        else             { a03 = a0; a13 = a1; }
    }

    // sparse events: flat f = 2*lane+e in [0,108) -> point f/27, offset f%27
    unsigned long long b0 = __ballot(lane < 54 && nv.x >= 0 && ((2 * lane    ) % 27) != 13);
    unsigned long long b1 = __ballot(lane < 54 && nv.y >= 0 && ((2 * lane + 1) % 27) != 13);
    while (b0) {
        const int L = __builtin_ctzll(b0); b0 &= b0 - 1;
        const int j = __shfl(nv.x, L);
        k1_event(2 * L, j, kh, c, feats, w00, a00, a01, a02, a03);
    }
    while (b1) {
        const int L = __builtin_ctzll(b1); b1 &= b1 - 1;
        const int j = __shfl(nv.y, L);
        k1_event(2 * L + 1, j, kh, c, feats, w00, a00, a01, a02, a03);
    }

    #pragma unroll
    for (int p = 0; p < 4; ++p) {
        float a0 = (p == 0) ? a00 : (p == 1) ? a01 : (p == 2) ? a02 : a03;
        float a1 = (p == 0) ? a10 : (p == 1) ? a11 : (p == 2) ? a12 : a13;
        a0 += __shfl_xor(a0, 32);
        a1 += __shfl_xor(a1, 32);
        const int i = i0 + p;
        if (kh == 0) h0[(size_t)i * 32 + c]    = fmaxf(a0, 0.f);
        else         t_out[(size_t)i * 32 + c] = fmaxf(a1, 0.f);
    }
}

__device__ __forceinline__ void k2_event(int f, int j, int kh, int c,
    const float* __restrict__ h0, const float* __restrict__ t_in,
    const float* __restrict__ w01, const float* __restrict__ w11,
    float& a00, float& a01, float& a02, float& a03,
    float& a10, float& a11, float& a12, float& a13)
{
    const int p = f / 27, o = f % 27;
    const f4* __restrict__ hr = reinterpret_cast<const f4*>(h0   + (size_t)j * 32 + kh * 16);
    const f4* __restrict__ tr = reinterpret_cast<const f4*>(t_in + (size_t)j * 32 + kh * 16);
    const float* __restrict__ wa = w01 + (size_t)(o * 32 + kh * 16) * 32 + c;
    const float* __restrict__ wb = w11 + (size_t)(o * 32 + kh * 16) * 32 + c;
    float a = 0.f, b = 0.f;
    #pragma unroll
    for (int q = 0; q < 4; ++q) {
        const f4 h = hr[q];
        a = fmaf(h.x, wa[(4*q+0)*32], a);
        a = fmaf(h.y, wa[(4*q+1)*32], a);
        a = fmaf(h.z, wa[(4*q+2)*32], a);
        a = fmaf(h.w, wa[(4*q+3)*32], a);
        const f4 u = tr[q];
        b = fmaf(u.x, wb[(4*q+0)*32], b);
        b = fmaf(u.y, wb[(4*q+1)*32], b);
        b = fmaf(u.z, wb[(4*q+2)*32], b);
        b = fmaf(u.w, wb[(4*q+3)*32], b);
    }
    if      (p == 0) { a00 += a; a10 += b; }
    else if (p == 1) { a01 += a; a11 += b; }
    else if (p == 2) { a02 += a; a12 += b; }
    else             { a03 += a; a13 += b; }
}

__global__ __launch_bounds__(256) void k2(
    const float* __restrict__ h0, const float* __restrict__ t_in,
    const float* __restrict__ w01, const float* __restrict__ w11,
    const float* __restrict__ w12, const float* __restrict__ feats,
    const int* __restrict__ nbr, float* __restrict__ out)
{
    __shared__ float2 hs[4][64];
    __shared__ float2 ts[4][64];
    const int tid  = threadIdx.x;
    const int lane = tid & 63;
    const int wv   = tid >> 6;
    const int c    = lane & 31;
    const int kh   = lane >> 5;
    const int i0   = blockIdx.x * 16 + wv * 4;

    const float2 hv = reinterpret_cast<const float2*>(h0   + (size_t)i0 * 32)[lane];
    const float2 tv = reinterpret_cast<const float2*>(t_in + (size_t)i0 * 32)[lane];
    int2 nv = make_int2(-1, -1);
    if (lane < 54) nv = reinterpret_cast<const int2*>(nbr + (size_t)i0 * 27)[lane];

    float wA[16], wB[16], wC[16];
    #pragma unroll
    for (int kk = 0; kk < 16; ++kk) {
        const int k = kh * 16 + kk;
        wA[kk] = w01[(size_t)(13 * 32 + k) * 32 + c];
        wB[kk] = w11[(size_t)(13 * 32 + k) * 32 + c];
        wC[kk] = w12[(size_t)k * 32 + c];
    }

    hs[wv][lane] = hv;
    ts[wv][lane] = tv;
    __syncthreads();      // harden LDS write->read ordering

    float a00 = 0, a01 = 0, a02 = 0, a03 = 0;   // conv0_1 path
    float a10 = 0, a11 = 0, a12 = 0, a13 = 0;   // conv1_1 path
    #pragma unroll
    for (int p = 0; p < 4; ++p) {
        const f4* hr = reinterpret_cast<const f4*>(&hs[wv][p * 16]) + kh * 4;
        const f4* tr = reinterpret_cast<const f4*>(&ts[wv][p * 16]) + kh * 4;
        float a0 = 0.f, a1 = 0.f;
        #pragma unroll
        for (int q = 0; q < 4; ++q) {
            const f4 h = hr[q];
            a0 = fmaf(h.x, wA[4*q+0], a0);
            a0 = fmaf(h.y, wA[4*q+1], a0);
            a0 = fmaf(h.z, wA[4*q+2], a0);
            a0 = fmaf(h.w, wA[4*q+3], a0);
            const f4 u = tr[q];
            a1 = fmaf(u.x, wB[4*q+0], a1);
            a1 = fmaf(u.y, wB[4*q+1], a1);
            a1 = fmaf(u.z, wB[4*q+2], a1);
            a1 = fmaf(u.w, wB[4*q+3], a1);
        }
        if      (p == 0) { a00 = a0; a10 = a1; }
        else if (p == 1) { a01 = a0; a11 = a1; }
        else if (p == 2) { a02 = a0; a12 = a1; }
        else             { a03 = a0; a13 = a1; }
    }

    unsigned long long b0 = __ballot(lane < 54 && nv.x >= 0 && ((2 * lane    ) % 27) != 13);
    unsigned long long b1 = __ballot(lane < 54 && nv.y >= 0 && ((2 * lane + 1) % 27) != 13);
    while (b0) {
        const int L = __builtin_ctzll(b0); b0 &= b0 - 1;
        const int j = __shfl(nv.x, L);
        k2_event(2 * L, j, kh, c, h0, t_in, w01, w11, a00, a01, a02, a03, a10, a11, a12, a13);
    }
    while (b1) {
        const int L = __builtin_ctzll(b1); b1 &= b1 - 1;
        const int j = __shfl(nv.y, L);
        k2_event(2 * L + 1, j, kh, c, h0, t_in, w01, w11, a00, a01, a02, a03, a10, a11, a12, a13);
    }

    // finalize: t2 = relu(conv1_1 full); out1 = t2 @ w12 via shfl broadcasts
    #pragma unroll
    for (int p = 0; p < 4; ++p) {
        float a0 = (p == 0) ? a00 : (p == 1) ? a01 : (p == 2) ? a02 : a03;
        float a1 = (p == 0) ? a10 : (p == 1) ? a11 : (p == 2) ? a12 : a13;
        a0 += __shfl_xor(a0, 32);
        a1 += __shfl_xor(a1, 32);
        const float t2 = fmaxf(a1, 0.f);   // full value for channel c, both halves
        float o1 = 0.f;
        #pragma unroll
        for (int kk = 0; kk < 16; ++kk) {
            const float tk = __shfl(t2, kh * 16 + kk);   // channel kh*16+kk
            o1 = fmaf(tk, wC[kk], o1);
        }
        o1 += __shfl_xor(o1, 32);
        const int i = i0 + p;
        const float res = feats[(size_t)i * 64 + kh * 32 + c];
        out[(size_t)i * 64 + kh * 32 + c] = (kh == 0 ? a0 : o1) + res;
    }
}

extern "C" void kernel_launch(void* const* d_in, const int* in_sizes, int n_in,
                              void* d_out, int out_size, void* d_ws, size_t ws_size,
                              hipStream_t stream)
{
    const float* feats = (const float*)d_in[0];
    const float* w00   = (const float*)d_in[1];
    const float* w01   = (const float*)d_in[2];
    const float* w10   = (const float*)d_in[3];
    const float* w11   = (const float*)d_in[4];
    const float* w12   = (const float*)d_in[5];
    const int*   nbr   = (const int*)d_in[6];
    float* out = (float*)d_out;

    float* h0 = (float*)d_ws;                  // [N,32] f32
    float* t  = h0 + (size_t)NPTS * 32;        // [N,32] f32

    const int blocks = NPTS / 16;              // 15625, exact
    k1<<<blocks, 256, 0, stream>>>(feats, w00, w10, nbr, h0, t);
    k2<<<blocks, 256, 0, stream>>>(h0, t, w01, w11, w12, feats, nbr, out);
}